// Round 6
// baseline (1505.764 us; speedup 1.0000x reference)
//
#include <hip/hip_runtime.h>

#define TT 2048
#define BQ 512
#define LAYERS 10
#define NC 7
#define CH 8               // timesteps per chunk (per barrier interval)
#define NCH (TT / CH)      // 256 chunks

// hs slot strides (dwords). Slot = [elem0: 16dw][elem1: 16dw] of f16
// pairs; pads zeroed once so MFMA A-frags read k=0..31 directly.
#define E_S 16
#define C_S (2 * E_S)              // 32
#define S_S (CH * C_S)             // 256
#define P_S ((LAYERS + 1) * S_S)   // 2816
#define GPW 224                    // gh scratch floats/layer: e*112+u*4+g
#define GXR 104                    // gx row stride (floats): row=2j+e;
                                   // 104%32=8 -> e0/e1 gather quads offset
                                   // by 2 -> ~even 7-per-quad spread

typedef _Float16 half2v __attribute__((ext_vector_type(2)));
typedef _Float16 f16x8 __attribute__((ext_vector_type(8)));
typedef float f32x4 __attribute__((ext_vector_type(4)));

__device__ __forceinline__ float sigm(float z) {
  return __builtin_amdgcn_rcpf(1.0f + __expf(-z));
}
__device__ __forceinline__ float dot2(unsigned w, unsigned v, float acc) {
  return __builtin_amdgcn_fdot2(__builtin_bit_cast(half2v, w),
                                __builtin_bit_cast(half2v, v), acc, false);
}
__device__ __forceinline__ unsigned pkh2(float a, float b) {
  union { _Float16 h[2]; unsigned u; } z;
  z.h[0] = (_Float16)a; z.h[1] = (_Float16)b;
  return z.u;
}

#define LOAD13(dst, src)                             \
  do {                                               \
    *(uint4*)&(dst)[0] = *(const uint4*)((src) + 0); \
    *(uint4*)&(dst)[4] = *(const uint4*)((src) + 4); \
    *(uint4*)&(dst)[8] = *(const uint4*)((src) + 8); \
    (dst)[12] = (src)[12];                           \
  } while (0)

// R14: chunk-batched x-side MFMA. R13 post-mortem: pipe-issue-bound
// (MfmaUtil 37 + VALUBusy 41); 8 of 14 MFMAs/cell were the x-side GEMM
// which has NO recurrence dep and used only 2/16 M-rows. Batch it:
// per chunk, A rows = (cell j, elem e) = all 16 M-rows -> 7 MFMAs/chunk
// (was 7/cell), scattered once to gx[16][GXR]. h-side: 7 MFMAs/cell,
// un-chained (no z4->Cr dep). MFMA/wave-step 112 -> 63. Activation now
// reads gx-quad + gh-quad and adds bias (f32 add replaces MFMA-internal
// accumulate; last-ulp only). Everything else unchanged from R13.
__launch_bounds__(768, 3)
__global__ void lstm_fused(const float* __restrict__ x,
                           const float* __restrict__ h0,
                           const float* __restrict__ c0,
                           const float* __restrict__ Wih,
                           const float* __restrict__ Whh,
                           const float* __restrict__ bias,
                           const float* __restrict__ fcw,
                           const float* __restrict__ fcb,
                           float* __restrict__ out) {
  __shared__ __align__(16) unsigned hs[2 * P_S];
  __shared__ __align__(16) float gx[LAYERS * 16 * GXR];  // x gate parts
  __shared__ __align__(16) float gp[LAYERS][GPW];        // h gate parts
  __shared__ float eb[2][CH][8];   // FC softmax exp staging

  const int tid = threadIdx.x;
  const int w = tid >> 6;          // 0..9 layers, 10/11 = FC+stage elem 0/1
  const int lane = tid & 63;
  const int b0 = blockIdx.x * 2;   // first batch elem of this block
  const int e = lane & 1;          // activation role: element
  const int u = lane >> 1;         // activation role: unit 0..24
  const int n15 = lane & 15;       // MFMA roles
  const int q4 = lane >> 4;
  const int arb = (n15 & 1) * E_S + 4 * q4;  // h-A-frag: row -> elem n15&1
  const int arb2 = (n15 >> 1) * C_S + (n15 & 1) * E_S + 4 * q4;  // x-A-frag
  const bool lay = (w < LAYERS);
  const bool isfc = (w >= LAYERS) && (lane < 7 * CH);
  const int efc = w - LAYERS;              // FC: which elem (0/1)
  const int jg = lane / 7;                 // FC: cell within chunk
  const int cls = lane - jg * 7;           // FC: class

  f16x8 BX[7], BH[7];              // B-frags: Wih / Whh, k=8*q4+j packing
  int ga[7];                       // gate scatter addrs (-1 = masked)
  unsigned Wf[13];                 // FC weights (f16 pairs)
  float bb[4] = {0.f, 0.f, 0.f, 0.f};
  float bf = 0.f;
  float c = 0.f;

  // FC-wave x staging roles: wave 10 -> elem 0, wave 11 -> elem 1.
  const int sgg = lane / 13;               // group 0..1 (lane<26)
  const int li = lane - sgg * 13;          // dword 0..12
  const int jb = sgg * 4;                  // first cell of this group
  const int i0 = 2 * li;
  const int i1 = (li < 12) ? (2 * li + 1) : 0;   // clamped in-bounds
  const bool stg = (w >= LAYERS) && (lane < 26);
  float xA[4], xB[4];
#pragma unroll
  for (int jj = 0; jj < 4; ++jj) { xA[jj] = 0.f; xB[jj] = 0.f; }

  // one-time zero of hs (pad dwords must read as 0 forever)
  for (int i = tid; i < 2 * P_S; i += 768) hs[i] = 0u;

  if (lay) {
#pragma unroll
    for (int nt = 0; nt < 7; ++nt) {
      const int G = 16 * nt + n15;         // gate row of this lane's B-col
      const bool gok = (G < 100);
      const float* px = Wih + (w * 100 + (gok ? G : 0)) * 25;
      const float* ph = Whh + (w * 100 + (gok ? G : 0)) * 25;
#pragma unroll
      for (int d = 0; d < 4; ++d) {
        const int k0 = 8 * q4 + 2 * d, k1 = k0 + 1;
        float x0 = 0.f, x1 = 0.f, h0v = 0.f, h1v = 0.f;
        if (gok && k0 < 25) { x0 = px[k0]; h0v = ph[k0]; }
        if (gok && k1 < 25) { x1 = px[k1]; h1v = ph[k1]; }
        BX[nt][2 * d]     = (_Float16)x0;
        BX[nt][2 * d + 1] = (_Float16)x1;
        BH[nt][2 * d]     = (_Float16)h0v;
        BH[nt][2 * d + 1] = (_Float16)h1v;
      }
      ga[nt] = gok ? ((G % 25) * 4 + (G / 25)) : -1;
    }
    if (lane < 50) {
#pragma unroll
      for (int r = 0; r < 4; ++r) bb[r] = bias[w * 100 + u + 25 * r];
      c = c0[(w * BQ + b0 + e) * 25 + u];
    }
  } else if (isfc) {
    const float* pf = fcw + cls * 25;
#pragma unroll
    for (int k = 0; k < 13; ++k) {
      const int k0 = 2 * k, k1 = 2 * k + 1;
      Wf[k] = pkh2(pf[k0], (k1 < 25) ? pf[k1] : 0.f);
    }
    bf = fcb[cls];
  }
  __syncthreads();   // zero-fill visible before pair staging

  // h0 -> packed pairs at [prev-parity of first active step][w+1][CH-1][e]
  {
    float h00 = 0.f;
    if (lay && lane < 50) h00 = h0[(w * BQ + b0 + e) * 25 + u];
    const float hn = __shfl_xor(h00, 2);   // same-elem neighbor unit u^1
    if (lay && lane < 50 && (lane & 2) == 0) {
      hs[((w & 1) ^ 1) * P_S + (w + 1) * S_S + (CH - 1) * C_S + e * E_S +
         (u >> 1)] = pkh2(h00, (u == 24) ? 0.f : hn);
    }
  }

  if (stg) {
    // chunk 0 -> parity 1 (read at m=0)
#pragma unroll
    for (int jj = 0; jj < 4; ++jj) {
      const float* p = x + ((size_t)(jb + jj) * BQ + (b0 + efc)) * 25;
      hs[1 * P_S + (jb + jj) * C_S + efc * E_S + li] =
          pkh2(p[i0], (li < 12) ? p[i1] : 0.f);
    }
    // preload chunk 1 into regs (staged to LDS at m=0)
#pragma unroll
    for (int jj = 0; jj < 4; ++jj) {
      const float* p = x + ((size_t)(CH + jb + jj) * BQ + (b0 + efc)) * 25;
      xA[jj] = p[i0];
      xB[jj] = (li < 12) ? p[i1] : 0.f;
    }
  }
  __syncthreads();

  for (int m = 0; m < NCH + LAYERS; ++m) {
    const int pr = (m & 1) ^ 1;                // read parity
    const int pw = m & 1;                      // write parity

    if (lay) {
      const int mc = m - w;                    // chunk index (wave-uniform)
      if ((unsigned)mc < (unsigned)NCH) {
        const unsigned* islot = hs + pr * P_S + w * S_S;
        const unsigned* o0p =
            hs + pr * P_S + (w + 1) * S_S + (CH - 1) * C_S + arb;
        unsigned* ob = hs + pw * P_S + (w + 1) * S_S;  // publish base
        const unsigned* obr = ob + arb;                // A-read view of own h
        float* gw = &gp[w][0];
        float* gxw = gx + w * 16 * GXR;

        // ---- chunk-batched x-side GEMM: A rows = (j,e), 7 MFMAs total
        {
          const f16x8 axc = __builtin_bit_cast(
              f16x8, *(const uint4*)(islot + arb2));
          const f32x4 z4 = {0.f, 0.f, 0.f, 0.f};
          f32x4 Cx[7];
#pragma unroll
          for (int nt = 0; nt < 7; ++nt) {
            Cx[nt] = __builtin_amdgcn_mfma_f32_16x16x32_f16(axc, BX[nt], z4,
                                                            0, 0, 0);
          }
          // scatter: lane holds rows 4*q4..4*q4+3 (=(j,e)) of col n15
#pragma unroll
          for (int nt = 0; nt < 7; ++nt) {
            if (ga[nt] >= 0) {
#pragma unroll
              for (int rr = 0; rr < 4; ++rr) {
                gxw[(4 * q4 + rr) * GXR + ga[nt]] = Cx[nt][rr];
              }
            }
          }
        }

        // ---- serial h-recurrence: 7 un-chained MFMAs per cell
#pragma unroll
        for (int j = 0; j < CH; ++j) {
          const uint4 ahu = (j == 0) ? *(const uint4*)o0p
                                     : *(const uint4*)(obr + (j - 1) * C_S);
          const f16x8 ah = __builtin_bit_cast(f16x8, ahu);
          const f32x4 z4 = {0.f, 0.f, 0.f, 0.f};
          f32x4 Cr[7];
#pragma unroll
          for (int nt = 0; nt < 7; ++nt) {
            Cr[nt] = __builtin_amdgcn_mfma_f32_16x16x32_f16(ah, BH[nt], z4,
                                                            0, 0, 0);
          }
          // scatter h-parts: reg0 = elem0 (C row0), reg1 = elem1 (row1)
          if (lane < 16) {
#pragma unroll
            for (int nt = 0; nt < 7; ++nt) {
              if (ga[nt] >= 0) {
                gw[ga[nt]]       = Cr[nt][0];
                gw[ga[nt] + 112] = Cr[nt][1];
              }
            }
          }
          // activations (same math; gate = gx + gh + bias)
          if (lane < 50) {
            const f32x4 gxv =
                *(const f32x4*)(gxw + (2 * j + e) * GXR + u * 4);
            const f32x4 ghv = *(const f32x4*)(gw + e * 112 + u * 4);
            const float gi = sigm(gxv[0] + ghv[0] + bb[0]);
            const float gf = sigm(gxv[1] + ghv[1] + bb[1]);
            const float pg = gxv[2] + ghv[2] + bb[2];
            const float gg = 2.0f * sigm(2.0f * pg) - 1.0f;  // tanh
            const float go = sigm(gxv[3] + ghv[3] + bb[3]);
            c = gf * c + gi * gg;
            const float th = 2.0f * sigm(2.0f * c) - 1.0f;   // tanh(c)
            const float hv = go * th;
            const float hn = __shfl_xor(hv, 2);  // same-elem neighbor unit
            if ((lane & 2) == 0) {               // even-u owners publish
              ob[j * C_S + e * E_S + (u >> 1)] =
                  pkh2(hv, (u == 24) ? 0.f : hn);
            }
          }
        }
      }
    } else {
      // FC waves: x staging for chunk m+1 / prefetch m+2 (stg lanes) ...
      if (stg) {
        if (m + 1 < NCH) {
#pragma unroll
          for (int jj = 0; jj < 4; ++jj) {
            hs[pw * P_S + (jb + jj) * C_S + efc * E_S + li] =
                pkh2(xA[jj], xB[jj]);
          }
        }
        if (m + 2 < NCH) {
          const size_t tb = (size_t)(m + 2) * CH + jb;
#pragma unroll
          for (int jj = 0; jj < 4; ++jj) {
            const float* p = x + ((tb + jj) * BQ + (b0 + efc)) * 25;
            xA[jj] = p[i0];
            xB[jj] = (li < 12) ? p[i1] : 0.f;
          }
        }
      }
      // ... and FC + softmax for elem efc: chunk mc = m-10 (parity pr)
      const int mc = m - LAYERS;
      if (isfc && (unsigned)mc < (unsigned)NCH) {
        const unsigned* hp =
            hs + pr * P_S + LAYERS * S_S + jg * C_S + efc * E_S;
        unsigned Hv[13];
        LOAD13(Hv, hp);
        float acc = bf;
#pragma unroll
        for (int k = 0; k < 13; ++k) acc = dot2(Wf[k], Hv[k], acc);
        const float ev = __expf(acc);           // logits small; no max-sub
        eb[efc][jg][cls] = ev;                  // same-wave LDS, ordered
        const float ssum = eb[efc][jg][0] + eb[efc][jg][1] + eb[efc][jg][2] +
                           eb[efc][jg][3] + eb[efc][jg][4] + eb[efc][jg][5] +
                           eb[efc][jg][6];
        const int t = mc * CH + jg;
        out[((size_t)t * BQ + (b0 + efc)) * NC + cls] =
            ev * __builtin_amdgcn_rcpf(ssum);
      }
    }
    __syncthreads();   // ONE barrier per chunk-step (266 total)
  }
}

extern "C" void kernel_launch(void* const* d_in, const int* in_sizes, int n_in,
                              void* d_out, int out_size, void* d_ws, size_t ws_size,
                              hipStream_t stream) {
  const float* x   = (const float*)d_in[0];
  const float* h0  = (const float*)d_in[1];
  const float* c0  = (const float*)d_in[2];
  const float* Wih = (const float*)d_in[3];
  const float* Whh = (const float*)d_in[4];
  const float* b   = (const float*)d_in[5];
  const float* fcw = (const float*)d_in[6];
  const float* fcb = (const float*)d_in[7];
  float* out = (float*)d_out;

  lstm_fused<<<dim3(256), dim3(768), 0, stream>>>(x, h0, c0, Wih, Whh, b, fcw,
                                                  fcb, out);
}

// Round 7
// 1245.235 us; speedup vs baseline: 1.2092x; 1.2092x over previous
//
#include <hip/hip_runtime.h>

#define TT 2048
#define BQ 512
#define LAYERS 10
#define NC 7
#define CH 8               // timesteps per chunk (per barrier interval)
#define NCH (TT / CH)      // 256 chunks

// hs slot strides (dwords). Slot = [elem0: 16dw][elem1: 16dw] of f16
// z-values (position p = component p); dwords 13-15 / halves 25-31 are
// ZERO (one-time memset) so MFMA A-frags read k=0..31 directly.
#define E_S 16
#define C_S (2 * E_S)              // 32
#define S_S (CH * C_S)             // 256
#define P_S ((LAYERS + 1) * S_S)   // 2816

typedef _Float16 half2v __attribute__((ext_vector_type(2)));
typedef _Float16 f16x8 __attribute__((ext_vector_type(8)));
typedef float f32x4 __attribute__((ext_vector_type(4)));

__device__ __forceinline__ float sigm(float z) {
  return __builtin_amdgcn_rcpf(1.0f + __expf(-z));
}
__device__ __forceinline__ float dot2(unsigned w, unsigned v, float acc) {
  return __builtin_amdgcn_fdot2(__builtin_bit_cast(half2v, w),
                                __builtin_bit_cast(half2v, v), acc, false);
}
__device__ __forceinline__ unsigned pkh2(float a, float b) {
  union { _Float16 h[2]; unsigned u; } z;
  z.h[0] = (_Float16)a; z.h[1] = (_Float16)b;
  return z.u;
}

#define LOAD13(dst, src)                             \
  do {                                               \
    *(uint4*)&(dst)[0] = *(const uint4*)((src) + 0); \
    *(uint4*)&(dst)[4] = *(const uint4*)((src) + 4); \
    *(uint4*)&(dst)[8] = *(const uint4*)((src) + 8); \
    (dst)[12] = (src)[12];                           \
  } while (0)

// R15: in-register gate activations -- no per-cell LDS scatter/gather.
// R14 post-mortem: serial-chain-bound, not MFMA-issue-bound; R14's gx
// scatter was a 4-way conflict (4*104 == 0 mod 32) ON the chain. Fix by
// CHOOSING the B-column->W-row map so MFMA output lands where it's used:
//   tile nt (0..7), col c: W row = 25*(nt&3) + (nt>=4 ? 16+c : c)
// -> lane (c,q4) holds the full (i,f,g,o) quad of unit u = c (+16 for
// hi tiles) in Cr[.][reg]. A = z duplicated across rows (row m = elem
// m&1; lane n15 loads elem n15&1 -- the SAME arb read R13/R14 verified)
// -> all C rows live -> act on 50 lanes: elem = q4&1 (reg select),
// unit-half = q4>>1 (tile select), both static-reg cndmasks. Publish =
// one ds_write_b16/lane (h[u] at half u). x-side chained as C-init
// (R13's exact numeric path). 16 MFMA/cell, zero LDS on the gate path.
__launch_bounds__(768, 3)
__global__ void lstm_fused(const float* __restrict__ x,
                           const float* __restrict__ h0,
                           const float* __restrict__ c0,
                           const float* __restrict__ Wih,
                           const float* __restrict__ Whh,
                           const float* __restrict__ bias,
                           const float* __restrict__ fcw,
                           const float* __restrict__ fcb,
                           float* __restrict__ out) {
  __shared__ __align__(16) unsigned hs[2 * P_S];
  __shared__ float eb[2][CH][8];   // FC softmax exp staging

  const int tid = threadIdx.x;
  const int w = tid >> 6;          // 0..9 layers, 10/11 = FC+stage elem 0/1
  const int lane = tid & 63;
  const int b0 = blockIdx.x * 2;   // first batch elem of this block
  const int n15 = lane & 15;
  const int q4 = lane >> 4;
  const int arb = (n15 & 1) * E_S + 4 * q4;  // A-frag: elem n15&1, k=8q4..
  const bool lay = (w < LAYERS);
  const int q4e = q4 & 1;                  // act: element (reg select)
  const bool q4hi = (q4 >= 2);             // act: unit-half (tile select)
  const int u = (q4hi ? 16 : 0) + n15;     // act: unit
  const bool av = lay && (!q4hi || (n15 < 9));   // 50 act-live lanes
  const bool isfc = (w >= LAYERS) && (lane < 7 * CH);
  const int efc = w - LAYERS;              // FC: which elem (0/1)
  const int jg = lane / 7;                 // FC: cell within chunk
  const int cls = lane - jg * 7;           // FC: class

  f16x8 BX[8], BH[8];              // B-frags (Wih/Whh), col-unit mapping
  unsigned Wf[13];                 // FC weights (f16 pairs)
  float bb[4] = {0.f, 0.f, 0.f, 0.f};
  float bf = 0.f;
  float c = 0.f;

  // FC-wave x staging roles: wave 10 -> elem 0, wave 11 -> elem 1.
  const int sgg = lane / 13;               // group 0..1 (lane<26)
  const int li = lane - sgg * 13;          // dword 0..12
  const int jb = sgg * 4;                  // first cell of this group
  const int i0 = 2 * li;
  const int i1 = (li < 12) ? (2 * li + 1) : 0;   // clamped in-bounds
  const bool stg = (w >= LAYERS) && (lane < 26);
  float xA[4], xB[4];
#pragma unroll
  for (int jj = 0; jj < 4; ++jj) { xA[jj] = 0.f; xB[jj] = 0.f; }

  // one-time zero of hs (pad halves must read as 0 forever)
  for (int i = tid; i < 2 * P_S; i += 768) hs[i] = 0u;

  if (lay) {
#pragma unroll
    for (int nt = 0; nt < 8; ++nt) {
      const int g = nt & 3;                // gate type i,f,g,o
      const int uu = ((nt >> 2) ? 16 : 0) + n15;     // unit of this col
      const bool gok = (uu < 25);
      const int row = 25 * g + (gok ? uu : 0);
      const float* px = Wih + (w * 100 + row) * 25;
      const float* ph = Whh + (w * 100 + row) * 25;
#pragma unroll
      for (int d = 0; d < 4; ++d) {
        const int k0 = 8 * q4 + 2 * d, k1 = k0 + 1;
        float x0 = 0.f, x1 = 0.f, h0v = 0.f, h1v = 0.f;
        if (gok && k0 < 25) { x0 = px[k0]; h0v = ph[k0]; }
        if (gok && k1 < 25) { x1 = px[k1]; h1v = ph[k1]; }
        BX[nt][2 * d]     = (_Float16)x0;
        BX[nt][2 * d + 1] = (_Float16)x1;
        BH[nt][2 * d]     = (_Float16)h0v;
        BH[nt][2 * d + 1] = (_Float16)h1v;
      }
    }
    if (av) {
#pragma unroll
      for (int g = 0; g < 4; ++g) bb[g] = bias[w * 100 + 25 * g + u];
      c = c0[(w * BQ + b0 + q4e) * 25 + u];
    }
  } else if (isfc) {
    const float* pf = fcw + cls * 25;
#pragma unroll
    for (int k = 0; k < 13; ++k) {
      const int k0 = 2 * k, k1 = 2 * k + 1;
      Wf[k] = pkh2(pf[k0], (k1 < 25) ? pf[k1] : 0.f);
    }
    bf = fcb[cls];
  }
  __syncthreads();   // zero-fill visible before staging

  // h0 -> f16 halves at [prev-parity of first active step][w+1][CH-1]
  if (av) {
    const float h00 = h0[(w * BQ + b0 + q4e) * 25 + u];
    _Float16* hp = (_Float16*)(hs + ((w & 1) ^ 1) * P_S + (w + 1) * S_S +
                               (CH - 1) * C_S);
    hp[q4e * 32 + u] = (_Float16)h00;
  }

  if (stg) {
    // chunk 0 -> parity 1 (read at m=0)
#pragma unroll
    for (int jj = 0; jj < 4; ++jj) {
      const float* p = x + ((size_t)(jb + jj) * BQ + (b0 + efc)) * 25;
      hs[1 * P_S + (jb + jj) * C_S + efc * E_S + li] =
          pkh2(p[i0], (li < 12) ? p[i1] : 0.f);
    }
    // preload chunk 1 into regs (staged to LDS at m=0)
#pragma unroll
    for (int jj = 0; jj < 4; ++jj) {
      const float* p = x + ((size_t)(CH + jb + jj) * BQ + (b0 + efc)) * 25;
      xA[jj] = p[i0];
      xB[jj] = (li < 12) ? p[i1] : 0.f;
    }
  }
  __syncthreads();

  for (int m = 0; m < NCH + LAYERS; ++m) {
    const int pr = (m & 1) ^ 1;                // read parity
    const int pw = m & 1;                      // write parity

    if (lay) {
      const int mc = m - w;                    // chunk index (wave-uniform)
      if ((unsigned)mc < (unsigned)NCH) {
        const unsigned* islot = hs + pr * P_S + w * S_S + arb;
        const unsigned* o0p =
            hs + pr * P_S + (w + 1) * S_S + (CH - 1) * C_S + arb;
        unsigned* ob = hs + pw * P_S + (w + 1) * S_S;  // publish base
        const unsigned* obr = ob + arb;                // A-view of own h

#pragma unroll
        for (int j = 0; j < CH; ++j) {
          const f16x8 ax =
              __builtin_bit_cast(f16x8, *(const uint4*)(islot + j * C_S));
          const uint4 ahu = (j == 0) ? *(const uint4*)o0p
                                     : *(const uint4*)(obr + (j - 1) * C_S);
          const f16x8 ah = __builtin_bit_cast(f16x8, ahu);
          f32x4 Cr[8];
#pragma unroll
          for (int nt = 0; nt < 8; ++nt) {
            f32x4 z4 = {0.f, 0.f, 0.f, 0.f};
            z4 = __builtin_amdgcn_mfma_f32_16x16x32_f16(ax, BX[nt], z4,
                                                        0, 0, 0);
            Cr[nt] = __builtin_amdgcn_mfma_f32_16x16x32_f16(ah, BH[nt], z4,
                                                            0, 0, 0);
          }
          if (av) {
            // static-reg quad select: tile = g + 4*q4hi, reg = q4e
            const float vi = q4hi ? (q4e ? Cr[4][1] : Cr[4][0])
                                  : (q4e ? Cr[0][1] : Cr[0][0]);
            const float vf = q4hi ? (q4e ? Cr[5][1] : Cr[5][0])
                                  : (q4e ? Cr[1][1] : Cr[1][0]);
            const float vg = q4hi ? (q4e ? Cr[6][1] : Cr[6][0])
                                  : (q4e ? Cr[2][1] : Cr[2][0]);
            const float vo = q4hi ? (q4e ? Cr[7][1] : Cr[7][0])
                                  : (q4e ? Cr[3][1] : Cr[3][0]);
            const float gi = sigm(vi + bb[0]);
            const float gf = sigm(vf + bb[1]);
            const float pg = vg + bb[2];
            const float gg = 2.0f * sigm(2.0f * pg) - 1.0f;  // tanh
            const float go = sigm(vo + bb[3]);
            c = gf * c + gi * gg;
            const float th = 2.0f * sigm(2.0f * c) - 1.0f;   // tanh(c)
            const float hv = go * th;
            _Float16* hp = (_Float16*)(ob + j * C_S);
            hp[q4e * 32 + u] = (_Float16)hv;   // one b16 publish per lane
          }
        }
      }
    } else {
      // FC waves: x staging for chunk m+1 / prefetch m+2 (stg lanes) ...
      if (stg) {
        if (m + 1 < NCH) {
#pragma unroll
          for (int jj = 0; jj < 4; ++jj) {
            hs[pw * P_S + (jb + jj) * C_S + efc * E_S + li] =
                pkh2(xA[jj], xB[jj]);
          }
        }
        if (m + 2 < NCH) {
          const size_t tb = (size_t)(m + 2) * CH + jb;
#pragma unroll
          for (int jj = 0; jj < 4; ++jj) {
            const float* p = x + ((tb + jj) * BQ + (b0 + efc)) * 25;
            xA[jj] = p[i0];
            xB[jj] = (li < 12) ? p[i1] : 0.f;
          }
        }
      }
      // ... and FC + softmax for elem efc: chunk mc = m-10 (parity pr)
      const int mc = m - LAYERS;
      if (isfc && (unsigned)mc < (unsigned)NCH) {
        const unsigned* hp =
            hs + pr * P_S + LAYERS * S_S + jg * C_S + efc * E_S;
        unsigned Hv[13];
        LOAD13(Hv, hp);
        float acc = bf;
#pragma unroll
        for (int k = 0; k < 13; ++k) acc = dot2(Wf[k], Hv[k], acc);
        const float ev = __expf(acc);           // logits small; no max-sub
        eb[efc][jg][cls] = ev;                  // same-wave LDS, ordered
        const float ssum = eb[efc][jg][0] + eb[efc][jg][1] + eb[efc][jg][2] +
                           eb[efc][jg][3] + eb[efc][jg][4] + eb[efc][jg][5] +
                           eb[efc][jg][6];
        const int t = mc * CH + jg;
        out[((size_t)t * BQ + (b0 + efc)) * NC + cls] =
            ev * __builtin_amdgcn_rcpf(ssum);
      }
    }
    __syncthreads();   // ONE barrier per chunk-step (266 total)
  }
}

extern "C" void kernel_launch(void* const* d_in, const int* in_sizes, int n_in,
                              void* d_out, int out_size, void* d_ws, size_t ws_size,
                              hipStream_t stream) {
  const float* x   = (const float*)d_in[0];
  const float* h0  = (const float*)d_in[1];
  const float* c0  = (const float*)d_in[2];
  const float* Wih = (const float*)d_in[3];
  const float* Whh = (const float*)d_in[4];
  const float* b   = (const float*)d_in[5];
  const float* fcw = (const float*)d_in[6];
  const float* fcb = (const float*)d_in[7];
  float* out = (float*)d_out;

  lstm_fused<<<dim3(256), dim3(768), 0, stream>>>(x, h0, c0, Wih, Whh, b, fcw,
                                                  fcb, out);
}